// Round 1
// 455.771 us; speedup vs baseline: 1.0461x; 1.0461x over previous
//
#include <hip/hip_runtime.h>
#include <hip/hip_bf16.h>

// Problem constants (B, K, D) from the reference.
#define B_SZ 4
#define K_SEQ 4096
#define D_DIM 2048
#define M_ROWS (B_SZ * K_SEQ)   // 16384 rows for the GEMM

// Scan chunking: 64 chunks of 64 timesteps
#define CHUNK 64
#define NCHUNK (K_SEQ / CHUNK)   // 64

typedef __attribute__((ext_vector_type(8))) short short8;   // 8 bf16 = 4 VGPRs
typedef __attribute__((ext_vector_type(4))) float floatx4;  // MFMA C/D frag
typedef __attribute__((ext_vector_type(8))) unsigned short ushortx8;

__device__ __forceinline__ unsigned short f2bf_rne(float f) {
  unsigned int u = __float_as_uint(f);
  u += 0x7fffu + ((u >> 16) & 1u);   // round-to-nearest-even
  return (unsigned short)(u >> 16);
}
__device__ __forceinline__ float bf2f(unsigned short u) {
  return __uint_as_float(((unsigned int)u) << 16);
}

// ---- fused fp32 -> bf16 conversion for x and W (one launch) ----
#define NX4 (M_ROWS * D_DIM / 4)   // 8388608 float4s of x
#define NW4 (D_DIM * D_DIM / 4)    // 1048576 float4s of W
__global__ void cvt_bf16_kernel(const float* __restrict__ x,
                                const float* __restrict__ W,
                                unsigned short* __restrict__ xb,
                                unsigned short* __restrict__ Wb) {
  int i = blockIdx.x * blockDim.x + threadIdx.x;
  const float* src;
  unsigned short* dst;
  int j;
  if (i < NX4) { src = x; dst = xb; j = i; }
  else         { src = W; dst = Wb; j = i - NX4; }
  float4 v = ((const float4*)src)[j];
  ushort4 o;
  o.x = f2bf_rne(v.x);
  o.y = f2bf_rne(v.y);
  o.z = f2bf_rne(v.z);
  o.w = f2bf_rne(v.w);
  ((ushort4*)dst)[j] = o;
}

// ---- async global->LDS, 16B per lane ----
__device__ __forceinline__ void gl_lds16(const void* g, void* l) {
  __builtin_amdgcn_global_load_lds(
      (const __attribute__((address_space(1))) unsigned int*)g,
      (__attribute__((address_space(3))) unsigned int*)l, 16, 0, 0);
}

// ======================================================================
// 256x256 tile, BK=64, 8-wave (2Mx4N), 8-phase schedule, counted vmcnt.
// LDS = ring of 4 slots at k-half (32-deep) granularity:
//   slot s (32KB): A region 256x32 bf16 (16KB) + B region 256x32 (16KB).
//   kh_idx = tile*2 + kh  (0..63 for K=2048);  slot = kh_idx & 3.
// Pair j (2 phases) computes k-step j: phase A = Mfrags 0-3 x Nfrags 0-3
// (8 ds_read: 4 B-frags + 4 A-frags), phase B = Mfrags 4-7 (4 ds_read,
// B-frags reused in regs). Stage: phase A stages A-matrix of kh j+3,
// phase B stages B-matrix of kh j+3 (slot freed at pair j-1 -> safe:
// its last ds_reads drained by pair j-1's lgkmcnt(0) before its final
// barrier). vmcnt(8) guard for pair j+1's slot sits BEFORE phase B's
// mid-barrier so the barrier publishes completion to all waves.
// Swizzle: physical 16B-chunk = logical_chunk ^ (row&3), applied on the
// staging SOURCE address and the ds_read address (both-sides, linear LDS
// dest for global_load_lds). Bank check: quad = 4*(lane&1) +
// ((lane>>4)^(lane&3)) -> exactly 8 lanes per bank-quad = conflict-free.
// ======================================================================
template <bool GBF>
__global__ __launch_bounds__(512, 2)
void gemm8_kernel(const unsigned short* __restrict__ Ag,
                  const unsigned short* __restrict__ Wg,
                  const float* __restrict__ bias,
                  void* __restrict__ lamv) {
  __shared__ __align__(16) unsigned short smem[65536];  // 128 KiB

  const int tid = threadIdx.x;
  const int lane = tid & 63;
  const int wave = tid >> 6;
  const int wr = wave >> 2;   // 0..1  (M half)
  const int wc = wave & 3;    // 0..3  (N quarter)
  // bn-stripe per XCD: consecutive blockIdx round-robin across XCDs,
  // so bid&7 pins one 1MB W-panel per XCD (L2-resident all run).
  const int bm = (blockIdx.x >> 3) * 256;
  const int bn = (blockIdx.x & 7) * 256;

  const int lane15 = lane & 15;
  // swizzled chunk offset, constant per thread (row&3 == lane&3 for all frags)
  const int choff = (((lane >> 4) ^ (lane & 3)) << 3);          // ushorts
  const int rA_off = (wr * 128 + lane15) * 32 + choff;          // ushorts
  const int rB_off = (wc * 64 + lane15) * 32 + choff;           // ushorts

  // staging: thread t covers row r_s = t>>2 (rounds add 128), chunk t&3
  const int r_s = tid >> 2;
  const int ch_l = (tid & 3) ^ (r_s & 3);   // inverse-swizzled source chunk
  const unsigned short* gA0 = Ag + (size_t)(bm + r_s) * D_DIM + ch_l * 8;
  const unsigned short* gA1 = gA0 + (size_t)128 * D_DIM;
  const unsigned short* gB0 = Wg + (size_t)(bn + r_s) * D_DIM + ch_l * 8;
  const unsigned short* gB1 = gB0 + (size_t)128 * D_DIM;
  const int st_off = tid * 8;   // ushorts (16B per lane, lane-linear)

  floatx4 acc[8][4];
#pragma unroll
  for (int i = 0; i < 8; ++i)
#pragma unroll
    for (int j = 0; j < 4; ++j)
      acc[i][j] = (floatx4){0.f, 0.f, 0.f, 0.f};

  // ---- prologue: stage kh 0,1,2 (12 loads/thread) ----
#pragma unroll
  for (int jt = 0; jt < 3; ++jt) {
    const int ts = jt * 16384;
    gl_lds16(gA0 + jt * 32, smem + ts + st_off);
    gl_lds16(gA1 + jt * 32, smem + ts + 4096 + st_off);
    gl_lds16(gB0 + jt * 32, smem + ts + 8192 + st_off);
    gl_lds16(gB1 + jt * 32, smem + ts + 12288 + st_off);
  }
  asm volatile("s_waitcnt vmcnt(8)" ::: "memory");  // kh0 (oldest 4) landed
  __builtin_amdgcn_s_barrier();

#define PAIR(J, STG, VMA)                                                     \
  {                                                                           \
    const int slot = (J) & 3;                                                 \
    const unsigned short* sA = smem + slot * 16384;                           \
    const unsigned short* sB = sA + 8192;                                     \
    short8 bfr[4], afr[4];                                                    \
    _Pragma("unroll") for (int nf = 0; nf < 4; ++nf)                          \
        bfr[nf] = *(const short8*)(sB + rB_off + nf * 512);                   \
    _Pragma("unroll") for (int mf = 0; mf < 4; ++mf)                          \
        afr[mf] = *(const short8*)(sA + rA_off + mf * 512);                   \
    if (STG) {                                                                \
      const int jt = (J) + 3;                                                 \
      const int ts = (jt & 3) * 16384;                                        \
      gl_lds16(gA0 + jt * 32, smem + ts + st_off);                            \
      gl_lds16(gA1 + jt * 32, smem + ts + 4096 + st_off);                     \
    }                                                                         \
    __builtin_amdgcn_s_barrier();                                             \
    asm volatile("s_waitcnt lgkmcnt(0)" ::: "memory");                        \
    __builtin_amdgcn_s_setprio(1);                                            \
    _Pragma("unroll") for (int mf = 0; mf < 4; ++mf)                          \
      _Pragma("unroll") for (int nf = 0; nf < 4; ++nf)                        \
        acc[mf][nf] = __builtin_amdgcn_mfma_f32_16x16x32_bf16(                \
            afr[mf], bfr[nf], acc[mf][nf], 0, 0, 0);                          \
    __builtin_amdgcn_s_setprio(0);                                            \
    __builtin_amdgcn_s_barrier();                                             \
    _Pragma("unroll") for (int mf = 0; mf < 4; ++mf)                          \
        afr[mf] = *(const short8*)(sA + rA_off + 2048 + mf * 512);            \
    if (STG) {                                                                \
      const int jt = (J) + 3;                                                 \
      const int ts = (jt & 3) * 16384 + 8192;                                 \
      gl_lds16(gB0 + jt * 32, smem + ts + st_off);                            \
      gl_lds16(gB1 + jt * 32, smem + ts + 4096 + st_off);                     \
    }                                                                         \
    if ((VMA) == 8) asm volatile("s_waitcnt vmcnt(8)" ::: "memory");          \
    else if ((VMA) == 4) asm volatile("s_waitcnt vmcnt(4)" ::: "memory");     \
    else if ((VMA) == 0) asm volatile("s_waitcnt vmcnt(0)" ::: "memory");     \
    __builtin_amdgcn_s_barrier();                                             \
    asm volatile("s_waitcnt lgkmcnt(0)" ::: "memory");                        \
    __builtin_amdgcn_s_setprio(1);                                            \
    _Pragma("unroll") for (int mf = 0; mf < 4; ++mf)                          \
      _Pragma("unroll") for (int nf = 0; nf < 4; ++nf)                        \
        acc[mf + 4][nf] = __builtin_amdgcn_mfma_f32_16x16x32_bf16(            \
            afr[mf], bfr[nf], acc[mf + 4][nf], 0, 0, 0);                      \
    __builtin_amdgcn_s_setprio(0);                                            \
    __builtin_amdgcn_s_barrier();                                             \
  }

#pragma unroll 4
  for (int j = 0; j < 60; ++j) PAIR(j, true, 8);
  PAIR(60, true, 8);    // stages kh63; guard kh61 (12 outstanding -> 8)
  PAIR(61, false, 4);   // guard kh62 (8 outstanding -> 4)
  PAIR(62, false, 0);   // guard kh63 (4 outstanding -> 0)
  PAIR(63, false, -1);  // no guard needed
#undef PAIR

  // Epilogue: C/D layout col=lane&15, row=(lane>>4)*4+reg  [m89/m91]
  const int crow = (lane >> 4) << 2;
#pragma unroll
  for (int nf = 0; nf < 4; ++nf) {
    const int ge = bn + wc * 64 + nf * 16 + lane15;
    const float bb = bias[ge];
#pragma unroll
    for (int mf = 0; mf < 8; ++mf) {
      const int gm0 = bm + wr * 128 + mf * 16 + crow;
#pragma unroll
      for (int r = 0; r < 4; ++r) {
        float v = acc[mf][nf][r] + bb;
        size_t off = (size_t)(gm0 + r) * D_DIM + ge;
        if constexpr (GBF) {
          // gamma = 1 - sigmoid(v) = 1/(1+e^v)
          float g = 1.0f / (1.0f + __expf(v));
          ((unsigned short*)lamv)[off] = f2bf_rne(g);
        } else {
          ((float*)lamv)[off] = 1.0f / (1.0f + __expf(-v));
        }
      }
    }
  }
}

// ======================= bf16-gamma scan path ============================
// Recurrence with gamma: s_t = s_{t-1} + g_t*(u_t - s_{t-1});  A-factor = (1-g).

// Pass 1: per-(b,chunk,d4) affine reduce. d4 granularity (8B/lane dual
// streams) doubles thread count vs d8 -> 512 blocks, better latency hiding.
__global__ void scan_reduce_bf(const unsigned short* __restrict__ gb,
                               const unsigned short* __restrict__ xb,
                               float* __restrict__ Ach,
                               float* __restrict__ Bch) {
  int idx = blockIdx.x * blockDim.x + threadIdx.x;  // < 131072
  int d4 = idx & 511;
  int c = (idx >> 9) & (NCHUNK - 1);
  int b = idx >> 15;
  size_t base = ((size_t)(b * K_SEQ + c * CHUNK)) * D_DIM + d4 * 4;
  float A[4], Bv[4];
#pragma unroll
  for (int j = 0; j < 4; ++j) { A[j] = 1.f; Bv[j] = 0.f; }
#pragma unroll 8
  for (int t = 0; t < CHUNK; ++t) {
    size_t o = base + (size_t)t * D_DIM;
    ushort4 g4 = *(const ushort4*)(gb + o);
    ushort4 u4 = *(const ushort4*)(xb + o);
    float g, u;
    g = bf2f(g4.x); u = bf2f(u4.x); A[0] -= g * A[0]; Bv[0] += g * (u - Bv[0]);
    g = bf2f(g4.y); u = bf2f(u4.y); A[1] -= g * A[1]; Bv[1] += g * (u - Bv[1]);
    g = bf2f(g4.z); u = bf2f(u4.z); A[2] -= g * A[2]; Bv[2] += g * (u - Bv[2]);
    g = bf2f(g4.w); u = bf2f(u4.w); A[3] -= g * A[3]; Bv[3] += g * (u - Bv[3]);
  }
  ((float4*)Ach)[idx] = make_float4(A[0], A[1], A[2], A[3]);
  ((float4*)Bch)[idx] = make_float4(Bv[0], Bv[1], Bv[2], Bv[3]);
}

// Mid pass: sequential prefix over chunks per chain (b, d4). fp32, unchanged.
__global__ void scan_prefix_kernel(const float* __restrict__ Ach,
                                   const float* __restrict__ Bch,
                                   float* __restrict__ Sst) {
  int idx = blockIdx.x * blockDim.x + threadIdx.x;  // < B*D/4 = 2048
  int d4 = idx & (D_DIM / 4 - 1);
  int b = idx >> 9;
  float4 s = make_float4(0.f, 0.f, 0.f, 0.f);
#pragma unroll 4
  for (int c = 0; c < NCHUNK; ++c) {
    int o4 = (b * NCHUNK + c) * (D_DIM / 4) + d4;
    ((float4*)Sst)[o4] = s;
    float4 A = ((const float4*)Ach)[o4];
    float4 Bv = ((const float4*)Bch)[o4];
    s.x = A.x * s.x + Bv.x;
    s.y = A.y * s.y + Bv.y;
    s.z = A.z * s.z + Bv.z;
    s.w = A.w * s.w + Bv.w;
  }
}

// Pass 2: apply with chunk-start state; writes fp32 output. d4 granularity.
__global__ void scan_apply_bf(const unsigned short* __restrict__ gb,
                              const unsigned short* __restrict__ xb,
                              const float* __restrict__ Sst,
                              float* __restrict__ out) {
  int idx = blockIdx.x * blockDim.x + threadIdx.x;  // < 131072
  int d4 = idx & 511;
  int c = (idx >> 9) & (NCHUNK - 1);
  int b = idx >> 15;
  size_t base = ((size_t)(b * K_SEQ + c * CHUNK)) * D_DIM + d4 * 4;
  float4 s4 = ((const float4*)Sst)[idx];
  float s[4] = {s4.x, s4.y, s4.z, s4.w};
#pragma unroll 8
  for (int t = 0; t < CHUNK; ++t) {
    size_t o = base + (size_t)t * D_DIM;
    ushort4 g4 = *(const ushort4*)(gb + o);
    ushort4 u4 = *(const ushort4*)(xb + o);
    s[0] += bf2f(g4.x) * (bf2f(u4.x) - s[0]);
    s[1] += bf2f(g4.y) * (bf2f(u4.y) - s[1]);
    s[2] += bf2f(g4.z) * (bf2f(u4.z) - s[2]);
    s[3] += bf2f(g4.w) * (bf2f(u4.w) - s[3]);
    *(float4*)(out + o) = make_float4(s[0], s[1], s[2], s[3]);
  }
}

// ======================= fp32-lambda fallback path =======================
__global__ void scan_reduce_kernel(const float* __restrict__ lam,
                                   const unsigned short* __restrict__ xb,
                                   float* __restrict__ Ach,
                                   float* __restrict__ Bch) {
  int idx = blockIdx.x * blockDim.x + threadIdx.x;
  int d4 = idx & (D_DIM / 4 - 1);
  int c = (idx >> 9) & (NCHUNK - 1);
  int b = idx >> 15;
  size_t base = ((size_t)(b * K_SEQ + c * CHUNK)) * D_DIM + d4 * 4;
  float4 Aacc = make_float4(1.f, 1.f, 1.f, 1.f);
  float4 Bv = make_float4(0.f, 0.f, 0.f, 0.f);
#pragma unroll 4
  for (int t = 0; t < CHUNK; ++t) {
    size_t o = base + (size_t)t * D_DIM;
    float4 l = *(const float4*)(lam + o);
    ushort4 ub = *(const ushort4*)(xb + o);
    Aacc.x *= l.x; Bv.x = l.x * (Bv.x - bf2f(ub.x)) + bf2f(ub.x);
    Aacc.y *= l.y; Bv.y = l.y * (Bv.y - bf2f(ub.y)) + bf2f(ub.y);
    Aacc.z *= l.z; Bv.z = l.z * (Bv.z - bf2f(ub.z)) + bf2f(ub.z);
    Aacc.w *= l.w; Bv.w = l.w * (Bv.w - bf2f(ub.w)) + bf2f(ub.w);
  }
  ((float4*)Ach)[idx] = Aacc;
  ((float4*)Bch)[idx] = Bv;
}

__global__ void scan_apply_kernel(float* lamout,
                                  const unsigned short* __restrict__ xb,
                                  const float* __restrict__ Sst) {
  int idx = blockIdx.x * blockDim.x + threadIdx.x;
  int d4 = idx & (D_DIM / 4 - 1);
  int c = (idx >> 9) & (NCHUNK - 1);
  int b = idx >> 15;
  size_t base = ((size_t)(b * K_SEQ + c * CHUNK)) * D_DIM + d4 * 4;
  float4 s = ((const float4*)Sst)[idx];
#pragma unroll 4
  for (int t = 0; t < CHUNK; ++t) {
    size_t o = base + (size_t)t * D_DIM;
    float4 l = *(const float4*)(lamout + o);
    ushort4 ub = *(const ushort4*)(xb + o);
    s.x = l.x * (s.x - bf2f(ub.x)) + bf2f(ub.x);
    s.y = l.y * (s.y - bf2f(ub.y)) + bf2f(ub.y);
    s.z = l.z * (s.z - bf2f(ub.z)) + bf2f(ub.z);
    s.w = l.w * (s.w - bf2f(ub.w)) + bf2f(ub.w);
    *(float4*)(lamout + o) = s;
  }
}

extern "C" void kernel_launch(void* const* d_in, const int* in_sizes, int n_in,
                              void* d_out, int out_size, void* d_ws, size_t ws_size,
                              hipStream_t stream) {
  const float* x = (const float*)d_in[0];    // [B,K,D] fp32
  const float* W = (const float*)d_in[1];    // [D,D] fp32
  const float* bias = (const float*)d_in[2]; // [D] fp32
  float* out = (float*)d_out;                // [B,K,D] fp32

  char* ws = (char*)d_ws;
  // bf16-gamma path workspace:
  //   x_bf  67108864 | W_bf 8388608 | g_bf 67108864 | Ach/Bch/Sst 3x2097152
  const size_t NEED_BF = 148897792ULL;
  const bool bfpath = (ws_size >= NEED_BF);  // constant per process -> capture-safe

  unsigned short* x_bf = (unsigned short*)ws;
  unsigned short* W_bf = (unsigned short*)(ws + 67108864ULL);

  // 1) fp32 -> bf16 conversions (x and W in one launch)
  cvt_bf16_kernel<<<(NX4 + NW4) / 256, 256, 0, stream>>>(x, W, x_bf, W_bf);

  dim3 ggrid((M_ROWS / 256) * (D_DIM / 256));  // 512 blocks, bn = bid&7

  if (bfpath) {
    unsigned short* g_bf = (unsigned short*)(ws + 75497472ULL);
    float* Ach = (float*)(ws + 142606336ULL);
    float* Bch = (float*)(ws + 144703488ULL);
    float* Sst = (float*)(ws + 146800640ULL);

    gemm8_kernel<true><<<ggrid, 512, 0, stream>>>(x_bf, W_bf, bias, g_bf);

    int total4 = B_SZ * NCHUNK * D_DIM / 4;  // 131072
    scan_reduce_bf<<<total4 / 256, 256, 0, stream>>>(g_bf, x_bf, Ach, Bch);
    scan_prefix_kernel<<<(B_SZ * D_DIM / 4) / 256, 256, 0, stream>>>(Ach, Bch, Sst);
    scan_apply_bf<<<total4 / 256, 256, 0, stream>>>(g_bf, x_bf, Sst, out);
  } else {
    // fallback: lambda fp32 in d_out, in-place apply (ws >= 82 MB)
    float* Ach = (float*)(ws + 75497472ULL);
    float* Bch = (float*)(ws + 77594624ULL);
    float* Sst = (float*)(ws + 79691776ULL);

    gemm8_kernel<false><<<ggrid, 512, 0, stream>>>(x_bf, W_bf, bias, out);

    int total4 = B_SZ * NCHUNK * D_DIM / 4;  // 131072
    scan_reduce_kernel<<<total4 / 256, 256, 0, stream>>>(out, x_bf, Ach, Bch);
    scan_prefix_kernel<<<(B_SZ * D_DIM / 4) / 256, 256, 0, stream>>>(Ach, Bch, Sst);
    scan_apply_kernel<<<total4 / 256, 256, 0, stream>>>(out, x_bf, Sst);
  }
}

// Round 3
// 439.552 us; speedup vs baseline: 1.0847x; 1.0369x over previous
//
#include <hip/hip_runtime.h>
#include <hip/hip_bf16.h>

// Problem constants (B, K, D) from the reference.
#define B_SZ 4
#define K_SEQ 4096
#define D_DIM 2048
#define M_ROWS (B_SZ * K_SEQ)   // 16384 rows for the GEMM

// Scan chunking: 128 chunks of 32 timesteps (512 blocks -> latency hiding)
#define CHUNK 32
#define NCHUNK (K_SEQ / CHUNK)   // 128

typedef __attribute__((ext_vector_type(8))) short short8;   // 8 bf16 = 4 VGPRs
typedef __attribute__((ext_vector_type(4))) float floatx4;  // MFMA C/D frag
typedef __attribute__((ext_vector_type(8))) unsigned short ushortx8;

__device__ __forceinline__ unsigned short f2bf_rne(float f) {
  unsigned int u = __float_as_uint(f);
  u += 0x7fffu + ((u >> 16) & 1u);   // round-to-nearest-even
  return (unsigned short)(u >> 16);
}
__device__ __forceinline__ float bf2f(unsigned short u) {
  return __uint_as_float(((unsigned int)u) << 16);
}

// ---- fused fp32 -> bf16 conversion for x and W (one launch) ----
#define NX4 (M_ROWS * D_DIM / 4)   // 8388608 float4s of x
#define NW4 (D_DIM * D_DIM / 4)    // 1048576 float4s of W
__global__ void cvt_bf16_kernel(const float* __restrict__ x,
                                const float* __restrict__ W,
                                unsigned short* __restrict__ xb,
                                unsigned short* __restrict__ Wb) {
  int i = blockIdx.x * blockDim.x + threadIdx.x;
  const float* src;
  unsigned short* dst;
  int j;
  if (i < NX4) { src = x; dst = xb; j = i; }
  else         { src = W; dst = Wb; j = i - NX4; }
  float4 v = ((const float4*)src)[j];
  ushort4 o;
  o.x = f2bf_rne(v.x);
  o.y = f2bf_rne(v.y);
  o.z = f2bf_rne(v.z);
  o.w = f2bf_rne(v.w);
  ((ushort4*)dst)[j] = o;
}

// ---- async global->LDS, 16B per lane ----
__device__ __forceinline__ void gl_lds16(const void* g, void* l) {
  __builtin_amdgcn_global_load_lds(
      (const __attribute__((address_space(1))) unsigned int*)g,
      (__attribute__((address_space(3))) unsigned int*)l, 16, 0, 0);
}

// ======================================================================
// 256x256 tile, BK=64, 8 waves (2Mx4N), m201-exact LDS geometry.
// LDS = 8 half-tile (HT) slots x 16KB. HT = [128 rows][64 k] bf16,
// 128B row stride, st_16x32 swizzle: phys_byte = byte ^ ((byte>>9&1)<<5)
// (flips col-bit4 by row-bit2). Staged via pre-inverse-swizzled global
// source + linear global_load_lds dest (involution, both-sides rule).
// HT types: 0=A rows[bm,+128) 1=B rows[bn,+128) 2=B rows[bn+128,+128)
// 3=A rows[bm+128,+128). slot(tile j, type t) = t + 4*(j&1).
// 4 phases per tile, reads 12/8/4/0 (frags register-held), ONE barrier
// per phase.
// CORRECTNESS RULE (R2 bug): tile j ph1 reads ALL FOUR HTs of tile j
// collectively (wave->HT assignment: wr picks A0/A1, wc picks B0/B1).
// So the guard before tile j's first read must certify all 8 staging
// loads of tile j. Guard = ph4's vmcnt(2) (leaves only A0(j+2) in
// flight) + barrier. Prologue likewise vmcnt(2). No other guards.
// Slot WAW safety: a slot staged at tile j ph_p was last read 2+
// barriers earlier with lgkm(0) drains in between (checked per-slot).
// ======================================================================
#define WAITVM_(n) asm volatile("s_waitcnt vmcnt(" #n ")" ::: "memory")
#define WAITVM(n) WAITVM_(n)

template <bool GBF>
__global__ __launch_bounds__(512, 2)
void gemm8_kernel(const unsigned short* __restrict__ Ag,
                  const unsigned short* __restrict__ Wg,
                  const float* __restrict__ bias,
                  void* __restrict__ lamv) {
  __shared__ __align__(16) unsigned short smem[65536];  // 128 KiB

  const int tid = threadIdx.x;
  const int lane = tid & 63;
  const int wave = tid >> 6;
  const int wr = wave >> 2;   // 0..1  (M half)
  const int wc = wave & 3;    // 0..3  (N quarter)
  // bn-stripe per XCD: consecutive blockIdx round-robin across XCDs,
  // so bid&7 pins one 1MB W-panel per XCD (L2-resident all run).
  const int bm = (blockIdx.x >> 3) * 256;
  const int bn = (blockIdx.x & 7) * 256;

  const int lane15 = lane & 15;
  const int tA = (wr == 0) ? 0 : 3;
  const int tB = (wc < 2) ? 1 : 2;
  // read swizzle: ushort addr = row*64 + ((ks*32 + kg*8) ^ sw16),
  // sw16 = ((row>>2)&1)<<4; row = 16*frag + lane15 -> row bit2 = lane bit2.
  const int sw16 = ((lane >> 2) & 1) << 4;
  const int kg8 = (lane >> 4) << 3;
  const int rA15 = lane15 * 64 + (kg8 ^ sw16);
  const int bb15 = ((wc & 1) << 12) + rA15;

  // staging: thread t covers phys bytes [16t,16t+16) of an HT slot
  // (rows 0..63; +4096 ushorts for rows 64..127); inverse-swizzled
  // logical source col (involution: same XOR as the read side).
  const int r_s = tid >> 3;                                   // 0..63
  const int lcol = (((tid & 7) ^ (((tid >> 5) & 1) << 1)) << 3);  // ushorts
  const unsigned short* gA0p = Ag + (size_t)(bm + r_s) * D_DIM + lcol;
  const unsigned short* gA1p = Ag + (size_t)(bm + 128 + r_s) * D_DIM + lcol;
  const unsigned short* gB0p = Wg + (size_t)(bn + r_s) * D_DIM + lcol;
  const unsigned short* gB1p = Wg + (size_t)(bn + 128 + r_s) * D_DIM + lcol;
  const int st8 = tid * 8;   // ushort offset (16B per lane, lane-linear)

#define STG(T, gp, jt)                                                        \
  {                                                                           \
    unsigned short* d_ = smem + (((T) + (((jt) & 1) << 2)) << 13) + st8;      \
    const unsigned short* s_ = (gp) + ((size_t)(jt) << 6);                    \
    gl_lds16(s_, d_);                                                         \
    gl_lds16(s_ + 64 * (size_t)D_DIM, d_ + 4096);                             \
  }

  floatx4 acc[8][4];
#pragma unroll
  for (int i = 0; i < 8; ++i)
#pragma unroll
    for (int j = 0; j < 4; ++j)
      acc[i][j] = (floatx4){0.f, 0.f, 0.f, 0.f};

#define MFMA16(AB, AF, BF)                                                    \
  _Pragma("unroll") for (int mf = 0; mf < 4; ++mf)                            \
  _Pragma("unroll") for (int nf = 0; nf < 4; ++nf)                            \
      acc[(AB) + mf][nf] = __builtin_amdgcn_mfma_f32_16x16x32_bf16(           \
          AF[mf], BF[nf], acc[(AB) + mf][nf], 0, 0, 0);

  // ---- prologue: A0(0), B0(0), A1(0), B1(0), A0(1)
  STG(0, gA0p, 0);
  STG(1, gB0p, 0);
  STG(3, gA1p, 0);
  STG(2, gB1p, 0);
  STG(0, gA0p, 1);
  WAITVM(2);   // ALL tile-0 HTs landed; only A0(1) in flight
  __builtin_amdgcn_s_barrier();

#define TILE(j, DOS1, DOS2, DOS4, V4)                                         \
  {                                                                           \
    const unsigned short* pA =                                                \
        smem + ((tA + (((j) & 1) << 2)) << 13) + rA15;                        \
    const unsigned short* pB =                                                \
        smem + ((tB + (((j) & 1) << 2)) << 13) + bb15;                        \
    short8 a0k0[4], a0k1[4], a1k0[4], a1k1[4], bk0[4], bk1[4];                \
    /* ---- ph1: reads for (mh0, both ks) + B ks0 ---- */                     \
    _Pragma("unroll") for (int mf = 0; mf < 4; ++mf) {                        \
      a0k0[mf] = *(const short8*)(pA + mf * 1024);                            \
      a0k1[mf] = *(const short8*)(pA + mf * 1024 + 32);                       \
    }                                                                         \
    _Pragma("unroll") for (int nf = 0; nf < 4; ++nf)                          \
        bk0[nf] = *(const short8*)(pB + nf * 1024);                           \
    if (DOS1) { STG(1, gB0p, (j) + 1); STG(3, gA1p, (j) + 1); }               \
    __builtin_amdgcn_s_barrier();                                             \
    asm volatile("s_waitcnt lgkmcnt(0)" ::: "memory");                        \
    __builtin_amdgcn_sched_barrier(0);                                        \
    __builtin_amdgcn_s_setprio(1);                                            \
    MFMA16(0, a0k0, bk0);                                                     \
    __builtin_amdgcn_s_setprio(0);                                            \
    /* ---- ph2: reads for (mh1, both ks) ---- */                             \
    _Pragma("unroll") for (int mf = 0; mf < 4; ++mf) {                        \
      a1k0[mf] = *(const short8*)(pA + 4096 + mf * 1024);                     \
      a1k1[mf] = *(const short8*)(pA + 4096 + mf * 1024 + 32);                \
    }                                                                         \
    if (DOS2) { STG(2, gB1p, (j) + 1); }                                      \
    __builtin_amdgcn_s_barrier();                                             \
    asm volatile("s_waitcnt lgkmcnt(0)" ::: "memory");                        \
    __builtin_amdgcn_sched_barrier(0);                                        \
    __builtin_amdgcn_s_setprio(1);                                            \
    MFMA16(4, a1k0, bk0);                                                     \
    __builtin_amdgcn_s_setprio(0);                                            \
    /* ---- ph3: reads B ks1 ---- */                                          \
    _Pragma("unroll") for (int nf = 0; nf < 4; ++nf)                          \
        bk1[nf] = *(const short8*)(pB + nf * 1024 + 32);                      \
    __builtin_amdgcn_s_barrier();                                             \
    asm volatile("s_waitcnt lgkmcnt(0)" ::: "memory");                        \
    __builtin_amdgcn_sched_barrier(0);                                        \
    __builtin_amdgcn_s_setprio(1);                                            \
    MFMA16(4, a1k1, bk1);                                                     \
    __builtin_amdgcn_s_setprio(0);                                            \
    /* ---- ph4: no reads (a0k1, bk1 register-held); guard certifies  */      \
    /* ALL FOUR HTs of tile j+1 (leaves only A0(j+2) in flight).      */      \
    if (DOS4) { STG(0, gA0p, (j) + 2); }                                      \
    if ((V4) == 2) { WAITVM(2); }                                             \
    else if ((V4) == 0) { WAITVM(0); }                                        \
    __builtin_amdgcn_s_barrier();                                             \
    asm volatile("s_waitcnt lgkmcnt(0)" ::: "memory");                        \
    __builtin_amdgcn_sched_barrier(0);                                        \
    __builtin_amdgcn_s_setprio(1);                                            \
    MFMA16(0, a0k1, bk1);                                                     \
    __builtin_amdgcn_s_setprio(0);                                            \
  }

#pragma unroll 2
  for (int j = 0; j < 30; ++j) TILE(j, 1, 1, 1, 2);
  TILE(30, 1, 1, 0, 0);   // stages tile-31 B0/A1/B1; drains everything
  TILE(31, 0, 0, 0, -1);  // no stage, no guard
#undef TILE
#undef STG
#undef MFMA16

  // Epilogue: C/D layout col=lane&15, row=(lane>>4)*4+reg  [m89/m91]
  const int crow = (lane >> 4) << 2;
#pragma unroll
  for (int nf = 0; nf < 4; ++nf) {
    const int ge = bn + wc * 64 + nf * 16 + lane15;
    const float bb = bias[ge];
#pragma unroll
    for (int mf = 0; mf < 8; ++mf) {
      const int gm0 = bm + wr * 128 + mf * 16 + crow;
#pragma unroll
      for (int r = 0; r < 4; ++r) {
        float v = acc[mf][nf][r] + bb;
        size_t off = (size_t)(gm0 + r) * D_DIM + ge;
        if constexpr (GBF) {
          // gamma = 1 - sigmoid(v) = 1/(1+e^v)
          float g = 1.0f / (1.0f + __expf(v));
          ((unsigned short*)lamv)[off] = f2bf_rne(g);
        } else {
          ((float*)lamv)[off] = 1.0f / (1.0f + __expf(-v));
        }
      }
    }
  }
}

// ======================= bf16-gamma scan path ============================
// Recurrence with gamma: s_t = s_{t-1} + g_t*(u_t - s_{t-1});  A-factor = (1-g).

// Pass 1: per-(b,chunk,d8) affine reduce, 16B/lane dual streams, 512 blocks.
__global__ void scan_reduce_bf(const unsigned short* __restrict__ gb,
                               const unsigned short* __restrict__ xb,
                               float* __restrict__ Ach,
                               float* __restrict__ Bch) {
  int idx = blockIdx.x * blockDim.x + threadIdx.x;  // < 131072
  int d8 = idx & 255;
  int c = (idx >> 8) & (NCHUNK - 1);
  int b = idx >> 15;
  size_t base = ((size_t)(b * K_SEQ + c * CHUNK)) * D_DIM + d8 * 8;
  float A[8], Bv[8];
#pragma unroll
  for (int j = 0; j < 8; ++j) { A[j] = 1.f; Bv[j] = 0.f; }
#pragma unroll 8
  for (int t = 0; t < CHUNK; ++t) {
    size_t o = base + (size_t)t * D_DIM;
    ushortx8 g8 = *(const ushortx8*)(gb + o);
    ushortx8 u8 = *(const ushortx8*)(xb + o);
#pragma unroll
    for (int j = 0; j < 8; ++j) {
      float g = bf2f(g8[j]), u = bf2f(u8[j]);
      A[j] -= g * A[j];          // A *= (1-g)
      Bv[j] += g * (u - Bv[j]);  // B = (1-g)B + g*u
    }
  }
  float4 a0 = make_float4(A[0], A[1], A[2], A[3]);
  float4 a1 = make_float4(A[4], A[5], A[6], A[7]);
  float4 b0 = make_float4(Bv[0], Bv[1], Bv[2], Bv[3]);
  float4 b1 = make_float4(Bv[4], Bv[5], Bv[6], Bv[7]);
  ((float4*)Ach)[idx * 2] = a0;
  ((float4*)Ach)[idx * 2 + 1] = a1;
  ((float4*)Bch)[idx * 2] = b0;
  ((float4*)Bch)[idx * 2 + 1] = b1;
}

// Mid pass: sequential prefix over chunks per chain (b, d4). fp32.
__global__ void scan_prefix_kernel(const float* __restrict__ Ach,
                                   const float* __restrict__ Bch,
                                   float* __restrict__ Sst) {
  int idx = blockIdx.x * blockDim.x + threadIdx.x;  // < B*D/4 = 2048
  int d4 = idx & (D_DIM / 4 - 1);
  int b = idx >> 9;
  float4 s = make_float4(0.f, 0.f, 0.f, 0.f);
#pragma unroll 4
  for (int c = 0; c < NCHUNK; ++c) {
    int o4 = (b * NCHUNK + c) * (D_DIM / 4) + d4;
    ((float4*)Sst)[o4] = s;
    float4 A = ((const float4*)Ach)[o4];
    float4 Bv = ((const float4*)Bch)[o4];
    s.x = A.x * s.x + Bv.x;
    s.y = A.y * s.y + Bv.y;
    s.z = A.z * s.z + Bv.z;
    s.w = A.w * s.w + Bv.w;
  }
}

// Pass 2: apply with chunk-start state; writes fp32 output.
__global__ void scan_apply_bf(const unsigned short* __restrict__ gb,
                              const unsigned short* __restrict__ xb,
                              const float* __restrict__ Sst,
                              float* __restrict__ out) {
  int idx = blockIdx.x * blockDim.x + threadIdx.x;  // < 131072
  int d8 = idx & 255;
  int c = (idx >> 8) & (NCHUNK - 1);
  int b = idx >> 15;
  size_t base = ((size_t)(b * K_SEQ + c * CHUNK)) * D_DIM + d8 * 8;
  float4 s0 = ((const float4*)Sst)[idx * 2];
  float4 s1 = ((const float4*)Sst)[idx * 2 + 1];
  float s[8] = {s0.x, s0.y, s0.z, s0.w, s1.x, s1.y, s1.z, s1.w};
#pragma unroll 8
  for (int t = 0; t < CHUNK; ++t) {
    size_t o = base + (size_t)t * D_DIM;
    ushortx8 g8 = *(const ushortx8*)(gb + o);
    ushortx8 u8 = *(const ushortx8*)(xb + o);
#pragma unroll
    for (int j = 0; j < 8; ++j) {
      float g = bf2f(g8[j]), u = bf2f(u8[j]);
      s[j] += g * (u - s[j]);
    }
    *(float4*)(out + o) = make_float4(s[0], s[1], s[2], s[3]);
    *(float4*)(out + o + 4) = make_float4(s[4], s[5], s[6], s[7]);
  }
}

// ======================= fp32-lambda fallback path =======================
__global__ void scan_reduce_kernel(const float* __restrict__ lam,
                                   const unsigned short* __restrict__ xb,
                                   float* __restrict__ Ach,
                                   float* __restrict__ Bch) {
  int idx = blockIdx.x * blockDim.x + threadIdx.x;
  int d4 = idx & (D_DIM / 4 - 1);
  int c = (idx >> 9) & (NCHUNK - 1);
  int b = idx >> 16;
  size_t base = ((size_t)(b * K_SEQ + c * CHUNK)) * D_DIM + d4 * 4;
  float4 Aacc = make_float4(1.f, 1.f, 1.f, 1.f);
  float4 Bv = make_float4(0.f, 0.f, 0.f, 0.f);
#pragma unroll 4
  for (int t = 0; t < CHUNK; ++t) {
    size_t o = base + (size_t)t * D_DIM;
    float4 l = *(const float4*)(lam + o);
    ushort4 ub = *(const ushort4*)(xb + o);
    Aacc.x *= l.x; Bv.x = l.x * (Bv.x - bf2f(ub.x)) + bf2f(ub.x);
    Aacc.y *= l.y; Bv.y = l.y * (Bv.y - bf2f(ub.y)) + bf2f(ub.y);
    Aacc.z *= l.z; Bv.z = l.z * (Bv.z - bf2f(ub.z)) + bf2f(ub.z);
    Aacc.w *= l.w; Bv.w = l.w * (Bv.w - bf2f(ub.w)) + bf2f(ub.w);
  }
  ((float4*)Ach)[idx] = Aacc;
  ((float4*)Bch)[idx] = Bv;
}

__global__ void scan_apply_kernel(float* lamout,
                                  const unsigned short* __restrict__ xb,
                                  const float* __restrict__ Sst) {
  int idx = blockIdx.x * blockDim.x + threadIdx.x;
  int d4 = idx & (D_DIM / 4 - 1);
  int c = (idx >> 9) & (NCHUNK - 1);
  int b = idx >> 16;
  size_t base = ((size_t)(b * K_SEQ + c * CHUNK)) * D_DIM + d4 * 4;
  float4 s = ((const float4*)Sst)[idx];
#pragma unroll 4
  for (int t = 0; t < CHUNK; ++t) {
    size_t o = base + (size_t)t * D_DIM;
    float4 l = *(const float4*)(lamout + o);
    ushort4 ub = *(const ushort4*)(xb + o);
    s.x = l.x * (s.x - bf2f(ub.x)) + bf2f(ub.x);
    s.y = l.y * (s.y - bf2f(ub.y)) + bf2f(ub.y);
    s.z = l.z * (s.z - bf2f(ub.z)) + bf2f(ub.z);
    s.w = l.w * (s.w - bf2f(ub.w)) + bf2f(ub.w);
    *(float4*)(lamout + o) = s;
  }
}

extern "C" void kernel_launch(void* const* d_in, const int* in_sizes, int n_in,
                              void* d_out, int out_size, void* d_ws, size_t ws_size,
                              hipStream_t stream) {
  const float* x = (const float*)d_in[0];    // [B,K,D] fp32
  const float* W = (const float*)d_in[1];    // [D,D] fp32
  const float* bias = (const float*)d_in[2]; // [D] fp32
  float* out = (float*)d_out;                // [B,K,D] fp32

  char* ws = (char*)d_ws;
  // bf16-gamma path workspace:
  //   x_bf 64MB | W_bf 8MB (dead after GEMM; Ach/Bch reuse it) | g_bf 64MB
  //   Ach 4MB @67108864 | Bch 4MB @71303168 | Sst 4MB @142606336
  const size_t NEED_BF = 148897792ULL;
  const bool bfpath = (ws_size >= NEED_BF);  // constant per process -> capture-safe

  unsigned short* x_bf = (unsigned short*)ws;
  unsigned short* W_bf = (unsigned short*)(ws + 67108864ULL);

  // 1) fp32 -> bf16 conversions (x and W in one launch)
  cvt_bf16_kernel<<<(NX4 + NW4) / 256, 256, 0, stream>>>(x, W, x_bf, W_bf);

  dim3 ggrid((M_ROWS / 256) * (D_DIM / 256));  // 512 blocks, bn = bid&7

  if (bfpath) {
    unsigned short* g_bf = (unsigned short*)(ws + 75497472ULL);
    float* Ach = (float*)(ws + 67108864ULL);   // over dead W_bf
    float* Bch = (float*)(ws + 71303168ULL);
    float* Sst = (float*)(ws + 142606336ULL);

    gemm8_kernel<true><<<ggrid, 512, 0, stream>>>(x_bf, W_bf, bias, g_bf);

    int total8 = B_SZ * NCHUNK * D_DIM / 8;  // 131072
    scan_reduce_bf<<<total8 / 256, 256, 0, stream>>>(g_bf, x_bf, Ach, Bch);
    scan_prefix_kernel<<<(B_SZ * D_DIM / 4) / 256, 256, 0, stream>>>(Ach, Bch, Sst);
    scan_apply_bf<<<total8 / 256, 256, 0, stream>>>(g_bf, x_bf, Sst, out);
  } else {
    // fallback: lambda fp32 in d_out, in-place apply
    float* Ach = (float*)(ws + 75497472ULL);
    float* Bch = (float*)(ws + 79691776ULL);
    float* Sst = (float*)(ws + 83886080ULL);

    gemm8_kernel<false><<<ggrid, 512, 0, stream>>>(x_bf, W_bf, bias, out);

    int total4 = B_SZ * NCHUNK * D_DIM / 4;  // 262144
    scan_reduce_kernel<<<total4 / 256, 256, 0, stream>>>(out, x_bf, Ach, Bch);
    scan_prefix_kernel<<<(B_SZ * D_DIM / 4) / 256, 256, 0, stream>>>(Ach, Bch, Sst);
    scan_apply_kernel<<<total4 / 256, 256, 0, stream>>>(out, x_bf, Sst);
  }
}

// Round 4
// 434.937 us; speedup vs baseline: 1.0962x; 1.0106x over previous
//
#include <hip/hip_runtime.h>
#include <hip/hip_bf16.h>

// Problem constants (B, K, D) from the reference.
#define B_SZ 4
#define K_SEQ 4096
#define D_DIM 2048
#define M_ROWS (B_SZ * K_SEQ)   // 16384 rows for the GEMM

// Scan chunking: 64 chunks of 64 timesteps (R0 config — best measured)
#define CHUNK 64
#define NCHUNK (K_SEQ / CHUNK)   // 64

typedef __attribute__((ext_vector_type(8))) short short8;   // 8 bf16 = 4 VGPRs
typedef __attribute__((ext_vector_type(4))) float floatx4;  // MFMA C/D frag
typedef __attribute__((ext_vector_type(8))) unsigned short ushortx8;

__device__ __forceinline__ unsigned short f2bf_rne(float f) {
  unsigned int u = __float_as_uint(f);
  u += 0x7fffu + ((u >> 16) & 1u);   // round-to-nearest-even
  return (unsigned short)(u >> 16);
}
__device__ __forceinline__ float bf2f(unsigned short u) {
  return __uint_as_float(((unsigned int)u) << 16);
}

// ---- fused fp32 -> bf16 conversion for x and W (one launch) ----
#define NX4 (M_ROWS * D_DIM / 4)   // 8388608 float4s of x
#define NW4 (D_DIM * D_DIM / 4)    // 1048576 float4s of W
__global__ void cvt_bf16_kernel(const float* __restrict__ x,
                                const float* __restrict__ W,
                                unsigned short* __restrict__ xb,
                                unsigned short* __restrict__ Wb) {
  int i = blockIdx.x * blockDim.x + threadIdx.x;
  const float* src;
  unsigned short* dst;
  int j;
  if (i < NX4) { src = x; dst = xb; j = i; }
  else         { src = W; dst = Wb; j = i - NX4; }
  float4 v = ((const float4*)src)[j];
  ushort4 o;
  o.x = f2bf_rne(v.x);
  o.y = f2bf_rne(v.y);
  o.z = f2bf_rne(v.z);
  o.w = f2bf_rne(v.w);
  ((ushort4*)dst)[j] = o;
}

// ---- async global->LDS, 16B per lane ----
__device__ __forceinline__ void gl_lds16(const void* g, void* l) {
  __builtin_amdgcn_global_load_lds(
      (const __attribute__((address_space(1))) unsigned int*)g,
      (__attribute__((address_space(3))) unsigned int*)l, 16, 0, 0);
}

// ======================================================================
// 256x256 tile, BK=64, 8 waves (2Mx4N).
// LDS = 8 half-tile (HT) slots x 16KB. HT = [128 rows][64 k] bf16,
// 128B row stride. SWIZZLE (R3 fix): phys_byte = byte ^ ((row&7)<<4)
// -- 3 row bits XOR'd into the bank-quad bits [6:4], so the 16-lane
// same-column fragment read spreads across all 8 quads (R1/R3's one-bit
// st_16x32 left a 4-way conflict: counter 1.258e7, identical both
// rounds). Consecutive-8 lanes (rows r..r+7, same kgrp) now hit 8
// distinct 16B quads -> conflict-free ds_read_b128.
// Since the XOR covers the ks-step bit (byte 64 = ushort bit 5), the
// ks=1 offset is k0off^32, NOT +32.
// Staged via pre-inverse-swizzled global source + linear
// global_load_lds dest (involution): thread t sources logical col
// ((t&7)^((t>>3)&7))<<3 ushorts (row+64 keeps row&7 -> same col).
// HT types: 0=A rows[bm,+128) 1=B rows[bn,+128) 2=B rows[bn+128,+128)
// 3=A rows[bm+128,+128). slot(tile j, type t) = t + 4*(j&1).
// 4 phases per tile, reads 12/8/4/0 (frags register-held), ONE barrier
// per phase. Guard: ph4 vmcnt(2) certifies ALL FOUR HTs of tile j+1
// (leaves only A0(j+2) in flight); prologue likewise vmcnt(2).
// ======================================================================
#define WAITVM_(n) asm volatile("s_waitcnt vmcnt(" #n ")" ::: "memory")
#define WAITVM(n) WAITVM_(n)

template <bool GBF>
__global__ __launch_bounds__(512, 2)
void gemm8_kernel(const unsigned short* __restrict__ Ag,
                  const unsigned short* __restrict__ Wg,
                  const float* __restrict__ bias,
                  void* __restrict__ lamv) {
  __shared__ __align__(16) unsigned short smem[65536];  // 128 KiB

  const int tid = threadIdx.x;
  const int lane = tid & 63;
  const int wave = tid >> 6;
  const int wr = wave >> 2;   // 0..1  (M half)
  const int wc = wave & 3;    // 0..3  (N quarter)
  // bn-stripe per XCD: consecutive blockIdx round-robin across XCDs,
  // so bid&7 pins one 1MB W-panel per XCD (L2-resident all run).
  const int bm = (blockIdx.x >> 3) * 256;
  const int bn = (blockIdx.x & 7) * 256;

  const int lane15 = lane & 15;
  const int tA = (wr == 0) ? 0 : 3;
  const int tB = (wc < 2) ? 1 : 2;
  // read swizzle (ushort units): swz = (row&7)<<3, row&7 == lane15&7.
  const int swz = (lane15 & 7) << 3;
  const int kg8 = (lane >> 4) << 3;
  const int k0off = kg8 ^ swz;          // ks=0 column, swizzled
  const int k1off = k0off ^ 32;         // ks=1: XOR the bit, not add
  const int rowoff = lane15 * 64;

  // staging: thread t covers phys bytes [16t,16t+16) of an HT slot
  // (rows 0..63; +4096 ushorts for rows 64..127); inverse-swizzled
  // logical source col (same 3-bit XOR involution as the read side).
  const int r_s = tid >> 3;                                        // 0..63
  const int lcol = (((tid & 7) ^ ((tid >> 3) & 7)) << 3);          // ushorts
  const unsigned short* gA0p = Ag + (size_t)(bm + r_s) * D_DIM + lcol;
  const unsigned short* gA1p = Ag + (size_t)(bm + 128 + r_s) * D_DIM + lcol;
  const unsigned short* gB0p = Wg + (size_t)(bn + r_s) * D_DIM + lcol;
  const unsigned short* gB1p = Wg + (size_t)(bn + 128 + r_s) * D_DIM + lcol;
  const int st8 = tid * 8;   // ushort offset (16B per lane, lane-linear)

#define STG(T, gp, jt)                                                        \
  {                                                                           \
    unsigned short* d_ = smem + (((T) + (((jt) & 1) << 2)) << 13) + st8;      \
    const unsigned short* s_ = (gp) + ((size_t)(jt) << 6);                    \
    gl_lds16(s_, d_);                                                         \
    gl_lds16(s_ + 64 * (size_t)D_DIM, d_ + 4096);                             \
  }

  floatx4 acc[8][4];
#pragma unroll
  for (int i = 0; i < 8; ++i)
#pragma unroll
    for (int j = 0; j < 4; ++j)
      acc[i][j] = (floatx4){0.f, 0.f, 0.f, 0.f};

#define MFMA16(AB, AF, BF)                                                    \
  _Pragma("unroll") for (int mf = 0; mf < 4; ++mf)                            \
  _Pragma("unroll") for (int nf = 0; nf < 4; ++nf)                            \
      acc[(AB) + mf][nf] = __builtin_amdgcn_mfma_f32_16x16x32_bf16(           \
          AF[mf], BF[nf], acc[(AB) + mf][nf], 0, 0, 0);

  // ---- prologue: A0(0), B0(0), A1(0), B1(0), A0(1)
  STG(0, gA0p, 0);
  STG(1, gB0p, 0);
  STG(3, gA1p, 0);
  STG(2, gB1p, 0);
  STG(0, gA0p, 1);
  WAITVM(2);   // ALL tile-0 HTs landed; only A0(1) in flight
  __builtin_amdgcn_s_barrier();

#define TILE(j, DOS1, DOS2, DOS4, V4)                                         \
  {                                                                           \
    const unsigned short* pA =                                                \
        smem + ((tA + (((j) & 1) << 2)) << 13) + rowoff;                      \
    const unsigned short* pB =                                                \
        smem + ((tB + (((j) & 1) << 2)) << 13) + ((wc & 1) << 12) + rowoff;   \
    short8 a0k0[4], a0k1[4], a1k0[4], a1k1[4], bk0[4], bk1[4];                \
    /* ---- ph1: reads for (mh0, both ks) + B ks0 ---- */                     \
    _Pragma("unroll") for (int mf = 0; mf < 4; ++mf) {                        \
      a0k0[mf] = *(const short8*)(pA + mf * 1024 + k0off);                    \
      a0k1[mf] = *(const short8*)(pA + mf * 1024 + k1off);                    \
    }                                                                         \
    _Pragma("unroll") for (int nf = 0; nf < 4; ++nf)                          \
        bk0[nf] = *(const short8*)(pB + nf * 1024 + k0off);                   \
    if (DOS1) { STG(1, gB0p, (j) + 1); STG(3, gA1p, (j) + 1); }               \
    __builtin_amdgcn_s_barrier();                                             \
    asm volatile("s_waitcnt lgkmcnt(0)" ::: "memory");                        \
    __builtin_amdgcn_sched_barrier(0);                                        \
    __builtin_amdgcn_s_setprio(1);                                            \
    MFMA16(0, a0k0, bk0);                                                     \
    __builtin_amdgcn_s_setprio(0);                                            \
    /* ---- ph2: reads for (mh1, both ks) ---- */                             \
    _Pragma("unroll") for (int mf = 0; mf < 4; ++mf) {                        \
      a1k0[mf] = *(const short8*)(pA + 4096 + mf * 1024 + k0off);             \
      a1k1[mf] = *(const short8*)(pA + 4096 + mf * 1024 + k1off);             \
    }                                                                         \
    if (DOS2) { STG(2, gB1p, (j) + 1); }                                      \
    __builtin_amdgcn_s_barrier();                                             \
    asm volatile("s_waitcnt lgkmcnt(0)" ::: "memory");                        \
    __builtin_amdgcn_sched_barrier(0);                                        \
    __builtin_amdgcn_s_setprio(1);                                            \
    MFMA16(4, a1k0, bk0);                                                     \
    __builtin_amdgcn_s_setprio(0);                                            \
    /* ---- ph3: reads B ks1 ---- */                                          \
    _Pragma("unroll") for (int nf = 0; nf < 4; ++nf)                          \
        bk1[nf] = *(const short8*)(pB + nf * 1024 + k1off);                   \
    __builtin_amdgcn_s_barrier();                                             \
    asm volatile("s_waitcnt lgkmcnt(0)" ::: "memory");                        \
    __builtin_amdgcn_sched_barrier(0);                                        \
    __builtin_amdgcn_s_setprio(1);                                            \
    MFMA16(4, a1k1, bk1);                                                     \
    __builtin_amdgcn_s_setprio(0);                                            \
    /* ---- ph4: no reads (a0k1, bk1 register-held); guard certifies  */      \
    /* ALL FOUR HTs of tile j+1 (leaves only A0(j+2) in flight).      */      \
    if (DOS4) { STG(0, gA0p, (j) + 2); }                                      \
    if ((V4) == 2) { WAITVM(2); }                                             \
    else if ((V4) == 0) { WAITVM(0); }                                        \
    __builtin_amdgcn_s_barrier();                                             \
    asm volatile("s_waitcnt lgkmcnt(0)" ::: "memory");                        \
    __builtin_amdgcn_sched_barrier(0);                                        \
    __builtin_amdgcn_s_setprio(1);                                            \
    MFMA16(0, a0k1, bk1);                                                     \
    __builtin_amdgcn_s_setprio(0);                                            \
  }

#pragma unroll 2
  for (int j = 0; j < 30; ++j) TILE(j, 1, 1, 1, 2);
  TILE(30, 1, 1, 0, 0);   // stages tile-31 B0/A1/B1; drains everything
  TILE(31, 0, 0, 0, -1);  // no stage, no guard
#undef TILE
#undef STG
#undef MFMA16

  // Epilogue: C/D layout col=lane&15, row=(lane>>4)*4+reg  [m89/m91]
  const int crow = (lane >> 4) << 2;
#pragma unroll
  for (int nf = 0; nf < 4; ++nf) {
    const int ge = bn + wc * 64 + nf * 16 + lane15;
    const float bb = bias[ge];
#pragma unroll
    for (int mf = 0; mf < 8; ++mf) {
      const int gm0 = bm + wr * 128 + mf * 16 + crow;
#pragma unroll
      for (int r = 0; r < 4; ++r) {
        float v = acc[mf][nf][r] + bb;
        size_t off = (size_t)(gm0 + r) * D_DIM + ge;
        if constexpr (GBF) {
          // gamma = 1 - sigmoid(v) = 1/(1+e^v)
          float g = 1.0f / (1.0f + __expf(v));
          ((unsigned short*)lamv)[off] = f2bf_rne(g);
        } else {
          ((float*)lamv)[off] = 1.0f / (1.0f + __expf(-v));
        }
      }
    }
  }
}

// ======================= bf16-gamma scan path ============================
// Recurrence with gamma: s_t = s_{t-1} + g_t*(u_t - s_{t-1});  A-factor = (1-g).

// Pass 1: per-(b,chunk,d8) affine reduce, 16B/lane dual streams (R0 config).
__global__ void scan_reduce_bf(const unsigned short* __restrict__ gb,
                               const unsigned short* __restrict__ xb,
                               float* __restrict__ Ach,
                               float* __restrict__ Bch) {
  int idx = blockIdx.x * blockDim.x + threadIdx.x;  // < 65536
  int d8 = idx & 255;
  int c = (idx >> 8) & (NCHUNK - 1);
  int b = idx >> 14;
  size_t base = ((size_t)(b * K_SEQ + c * CHUNK)) * D_DIM + d8 * 8;
  float A[8], Bv[8];
#pragma unroll
  for (int j = 0; j < 8; ++j) { A[j] = 1.f; Bv[j] = 0.f; }
#pragma unroll 8
  for (int t = 0; t < CHUNK; ++t) {
    size_t o = base + (size_t)t * D_DIM;
    ushortx8 g8 = *(const ushortx8*)(gb + o);
    ushortx8 u8 = *(const ushortx8*)(xb + o);
#pragma unroll
    for (int j = 0; j < 8; ++j) {
      float g = bf2f(g8[j]), u = bf2f(u8[j]);
      A[j] -= g * A[j];          // A *= (1-g)
      Bv[j] += g * (u - Bv[j]);  // B = (1-g)B + g*u
    }
  }
  float4 a0 = make_float4(A[0], A[1], A[2], A[3]);
  float4 a1 = make_float4(A[4], A[5], A[6], A[7]);
  float4 b0 = make_float4(Bv[0], Bv[1], Bv[2], Bv[3]);
  float4 b1 = make_float4(Bv[4], Bv[5], Bv[6], Bv[7]);
  ((float4*)Ach)[idx * 2] = a0;
  ((float4*)Ach)[idx * 2 + 1] = a1;
  ((float4*)Bch)[idx * 2] = b0;
  ((float4*)Bch)[idx * 2 + 1] = b1;
}

// Mid pass: sequential prefix over chunks, d1 granularity (8192 chains =
// 4x the old d4 parallelism; same linear float layout as both appliers).
__global__ void scan_prefix_kernel(const float* __restrict__ Ach,
                                   const float* __restrict__ Bch,
                                   float* __restrict__ Sst) {
  int idx = blockIdx.x * blockDim.x + threadIdx.x;  // < B*D = 8192
  int d = idx & (D_DIM - 1);
  int b = idx >> 11;
  float s = 0.f;
#pragma unroll 4
  for (int c = 0; c < NCHUNK; ++c) {
    int o = (b * NCHUNK + c) * D_DIM + d;
    Sst[o] = s;
    s = Ach[o] * s + Bch[o];
  }
}

// Pass 2: apply with chunk-start state; writes fp32 output (R0 config).
__global__ void scan_apply_bf(const unsigned short* __restrict__ gb,
                              const unsigned short* __restrict__ xb,
                              const float* __restrict__ Sst,
                              float* __restrict__ out) {
  int idx = blockIdx.x * blockDim.x + threadIdx.x;  // < 65536
  int d8 = idx & 255;
  int c = (idx >> 8) & (NCHUNK - 1);
  int b = idx >> 14;
  size_t base = ((size_t)(b * K_SEQ + c * CHUNK)) * D_DIM + d8 * 8;
  float4 s0 = ((const float4*)Sst)[idx * 2];
  float4 s1 = ((const float4*)Sst)[idx * 2 + 1];
  float s[8] = {s0.x, s0.y, s0.z, s0.w, s1.x, s1.y, s1.z, s1.w};
#pragma unroll 8
  for (int t = 0; t < CHUNK; ++t) {
    size_t o = base + (size_t)t * D_DIM;
    ushortx8 g8 = *(const ushortx8*)(gb + o);
    ushortx8 u8 = *(const ushortx8*)(xb + o);
#pragma unroll
    for (int j = 0; j < 8; ++j) {
      float g = bf2f(g8[j]), u = bf2f(u8[j]);
      s[j] += g * (u - s[j]);
    }
    *(float4*)(out + o) = make_float4(s[0], s[1], s[2], s[3]);
    *(float4*)(out + o + 4) = make_float4(s[4], s[5], s[6], s[7]);
  }
}

// ======================= fp32-lambda fallback path =======================
__global__ void scan_reduce_kernel(const float* __restrict__ lam,
                                   const unsigned short* __restrict__ xb,
                                   float* __restrict__ Ach,
                                   float* __restrict__ Bch) {
  int idx = blockIdx.x * blockDim.x + threadIdx.x;  // < 131072
  int d4 = idx & (D_DIM / 4 - 1);
  int c = (idx >> 9) & (NCHUNK - 1);
  int b = idx >> 15;
  size_t base = ((size_t)(b * K_SEQ + c * CHUNK)) * D_DIM + d4 * 4;
  float4 Aacc = make_float4(1.f, 1.f, 1.f, 1.f);
  float4 Bv = make_float4(0.f, 0.f, 0.f, 0.f);
#pragma unroll 4
  for (int t = 0; t < CHUNK; ++t) {
    size_t o = base + (size_t)t * D_DIM;
    float4 l = *(const float4*)(lam + o);
    ushort4 ub = *(const ushort4*)(xb + o);
    Aacc.x *= l.x; Bv.x = l.x * (Bv.x - bf2f(ub.x)) + bf2f(ub.x);
    Aacc.y *= l.y; Bv.y = l.y * (Bv.y - bf2f(ub.y)) + bf2f(ub.y);
    Aacc.z *= l.z; Bv.z = l.z * (Bv.z - bf2f(ub.z)) + bf2f(ub.z);
    Aacc.w *= l.w; Bv.w = l.w * (Bv.w - bf2f(ub.w)) + bf2f(ub.w);
  }
  ((float4*)Ach)[idx] = Aacc;
  ((float4*)Bch)[idx] = Bv;
}

__global__ void scan_apply_kernel(float* lamout,
                                  const unsigned short* __restrict__ xb,
                                  const float* __restrict__ Sst) {
  int idx = blockIdx.x * blockDim.x + threadIdx.x;  // < 131072
  int d4 = idx & (D_DIM / 4 - 1);
  int c = (idx >> 9) & (NCHUNK - 1);
  int b = idx >> 15;
  size_t base = ((size_t)(b * K_SEQ + c * CHUNK)) * D_DIM + d4 * 4;
  float4 s = ((const float4*)Sst)[idx];
#pragma unroll 4
  for (int t = 0; t < CHUNK; ++t) {
    size_t o = base + (size_t)t * D_DIM;
    float4 l = *(const float4*)(lamout + o);
    ushort4 ub = *(const ushort4*)(xb + o);
    s.x = l.x * (s.x - bf2f(ub.x)) + bf2f(ub.x);
    s.y = l.y * (s.y - bf2f(ub.y)) + bf2f(ub.y);
    s.z = l.z * (s.z - bf2f(ub.z)) + bf2f(ub.z);
    s.w = l.w * (s.w - bf2f(ub.w)) + bf2f(ub.w);
    *(float4*)(lamout + o) = s;
  }
}

extern "C" void kernel_launch(void* const* d_in, const int* in_sizes, int n_in,
                              void* d_out, int out_size, void* d_ws, size_t ws_size,
                              hipStream_t stream) {
  const float* x = (const float*)d_in[0];    // [B,K,D] fp32
  const float* W = (const float*)d_in[1];    // [D,D] fp32
  const float* bias = (const float*)d_in[2]; // [D] fp32
  float* out = (float*)d_out;                // [B,K,D] fp32

  char* ws = (char*)d_ws;
  // bf16-gamma path workspace:
  //   x_bf 64MB | W_bf 8MB (dead after GEMM; Ach/Bch reuse it) | g_bf 64MB
  //   Ach 2MB @67108864 | Bch 2MB @71303168 | Sst 2MB @142606336
  const size_t NEED_BF = 148897792ULL;
  const bool bfpath = (ws_size >= NEED_BF);  // constant per process -> capture-safe

  unsigned short* x_bf = (unsigned short*)ws;
  unsigned short* W_bf = (unsigned short*)(ws + 67108864ULL);

  // 1) fp32 -> bf16 conversions (x and W in one launch)
  cvt_bf16_kernel<<<(NX4 + NW4) / 256, 256, 0, stream>>>(x, W, x_bf, W_bf);

  dim3 ggrid((M_ROWS / 256) * (D_DIM / 256));  // 512 blocks, bn = bid&7

  if (bfpath) {
    unsigned short* g_bf = (unsigned short*)(ws + 75497472ULL);
    float* Ach = (float*)(ws + 67108864ULL);   // over dead W_bf
    float* Bch = (float*)(ws + 71303168ULL);
    float* Sst = (float*)(ws + 142606336ULL);

    gemm8_kernel<true><<<ggrid, 512, 0, stream>>>(x_bf, W_bf, bias, g_bf);

    int total8 = B_SZ * NCHUNK * D_DIM / 8;  // 65536
    scan_reduce_bf<<<total8 / 256, 256, 0, stream>>>(g_bf, x_bf, Ach, Bch);
    scan_prefix_kernel<<<(B_SZ * D_DIM) / 256, 256, 0, stream>>>(Ach, Bch, Sst);
    scan_apply_bf<<<total8 / 256, 256, 0, stream>>>(g_bf, x_bf, Sst, out);
  } else {
    // fallback: lambda fp32 in d_out, in-place apply
    float* Ach = (float*)(ws + 75497472ULL);
    float* Bch = (float*)(ws + 79691776ULL);
    float* Sst = (float*)(ws + 83886080ULL);

    gemm8_kernel<false><<<ggrid, 512, 0, stream>>>(x_bf, W_bf, bias, out);

    int total4 = B_SZ * NCHUNK * D_DIM / 4;  // 131072
    scan_reduce_kernel<<<total4 / 256, 256, 0, stream>>>(out, x_bf, Ach, Bch);
    scan_prefix_kernel<<<(B_SZ * D_DIM) / 256, 256, 0, stream>>>(Ach, Bch, Sst);
    scan_apply_kernel<<<total4 / 256, 256, 0, stream>>>(out, x_bf, Sst);
  }
}